// Round 9
// baseline (214.039 us; speedup 1.0000x reference)
//
#include <hip/hip_runtime.h>
#include <hip/hip_bf16.h>

#define B_ 8
#define S_ 2048
#define H_ 256
#define BS_ (B_*S_)

typedef __attribute__((ext_vector_type(8))) short bf16x8;
typedef __attribute__((ext_vector_type(4))) short bf16x4;
typedef __attribute__((ext_vector_type(4))) float f32x4;

static __device__ inline short f2bf(float f) {
  union { float f; unsigned int u; } a; a.f = f;
  unsigned int u = a.u;
  unsigned int r = (u + 0x7fffu + ((u >> 16) & 1u)) >> 16;
  return (short)r;
}

static __device__ inline float bf2f(short s) {
  union { float f; unsigned int u; } a;
  a.u = ((unsigned int)(unsigned short)s) << 16;
  return a.f;
}

static __device__ inline f32x4 mfma16(bf16x8 a, bf16x8 b, f32x4 c) {
  return __builtin_amdgcn_mfma_f32_16x16x32_bf16(a, b, c, 0, 0, 0);
}

// async global(16B/lane) -> LDS(wave-uniform base + lane*16)
static __device__ inline void gl_lds16(const short* g, short* l) {
  __builtin_amdgcn_global_load_lds(
      (const __attribute__((address_space(1))) void*)g,
      (__attribute__((address_space(3))) void*)l, 16, 0, 0);
}

// ---------------------------------------------------------------------------
// Kernel 0: fp32 -> bf16 conversion of x, Wq, Wk, Wv + zero den accumulator.
// ---------------------------------------------------------------------------
#define NX4 (BS_ * H_ / 4)
#define NW4 (H_ * H_ / 4)
#define NTOT4 (NX4 + 3 * NW4)
#define NALL4 (NTOT4 + BS_ / 4)

__global__ __launch_bounds__(256) void cvt_bf16(
    const float* __restrict__ x,
    const float* __restrict__ Wq, const float* __restrict__ Wk,
    const float* __restrict__ Wv,
    short* __restrict__ xb, short* __restrict__ wqb,
    short* __restrict__ wkb, short* __restrict__ wvb,
    float* __restrict__ den)
{
  int stride = gridDim.x * blockDim.x;
  for (int i = blockIdx.x * blockDim.x + threadIdx.x; i < NALL4; i += stride) {
    if (i >= NTOT4) {                        // zero den (0xAA-poisoned ws)
      float4 z = {0.f, 0.f, 0.f, 0.f};
      *(float4*)(den + (size_t)(i - NTOT4) * 4) = z;
      continue;
    }
    const float* src; short* dst; int off;
    if (i < NX4) { src = x; dst = xb; off = i; }
    else {
      int j = i - NX4;
      int w = j >> 14;
      off = j & (NW4 - 1);
      src = (w == 0) ? Wq : (w == 1) ? Wk : Wv;
      dst = (w == 0) ? wqb : (w == 1) ? wkb : wvb;
    }
    float4 v = *(const float4*)(src + off * 4);
    bf16x4 p;
    p[0] = f2bf(v.x); p[1] = f2bf(v.y); p[2] = f2bf(v.z); p[3] = f2bf(v.w);
    *(bf16x4*)(dst + off * 4) = p;
  }
}

// ---------------------------------------------------------------------------
// Kernel 1: Q/K row-major + V transposed [b][h][k]. grid (BS/64, 3), block 256.
// LDS-staged; wave = 64s x 64c (4A x 4B = 16 MFMA/chunk, 8 KB ds_read/chunk).
// ---------------------------------------------------------------------------
__global__ __launch_bounds__(256) void qkv_proj(
    const short* __restrict__ x,
    const short* __restrict__ Wq, const float* __restrict__ bq,
    const short* __restrict__ Wk, const float* __restrict__ bk,
    const short* __restrict__ Wv, const float* __restrict__ bv,
    short* __restrict__ Qo, short* __restrict__ Ko, short* __restrict__ VTo)
{
  const int tid  = threadIdx.x;
  const int wave = tid >> 6;
  const int lane = tid & 63;
  const int quad = lane >> 4;
  const int l16  = lane & 15;
  const int y    = blockIdx.y;

  const short* W    = (y == 0) ? Wq : (y == 1) ? Wk : Wv;
  const float* bias = (y == 0) ? bq : (y == 1) ? bk : bv;
  const int sblk = blockIdx.x * 64;

  __shared__ short wbuf[16 * 512];   // all 256 W-rows x 32-K chunk
  __shared__ short xbuf[4 * 512];    // 64 X-rows x 32-K chunk

  f32x4 zero = {0.f, 0.f, 0.f, 0.f};
  f32x4 acc[4][4];                   // [s-tile][nf-rel]
#pragma unroll
  for (int i = 0; i < 4; i++)
#pragma unroll
    for (int j = 0; j < 4; j++) acc[i][j] = zero;

  for (int ch = 0; ch < 8; ch++) {
#pragma unroll
    for (int i = 0; i < 4; i++) {
      int r = wave * 4 + i;
      gl_lds16(W + (r * 16 + l16) * H_ + ch * 32 + quad * 8, wbuf + r * 512);
    }
    gl_lds16(x + (sblk + wave * 16 + l16) * H_ + ch * 32 + quad * 8,
             xbuf + wave * 512);
    __syncthreads();
    bf16x8 af[4];
#pragma unroll
    for (int st = 0; st < 4; st++)
      af[st] = *(const bf16x8*)(xbuf + st * 512 + lane * 8);
#pragma unroll
    for (int i = 0; i < 4; i++) {
      bf16x8 bb = *(const bf16x8*)(wbuf + (wave * 4 + i) * 512 + lane * 8);
#pragma unroll
      for (int st = 0; st < 4; st++)
        acc[st][i] = mfma16(af[st], bb, acc[st][i]);
    }
    __syncthreads();
  }

  if (y < 2) {
    short* dst = (y == 0) ? Qo : Ko;
#pragma unroll
    for (int i = 0; i < 4; i++) {
      int col = (wave * 4 + i) * 16 + l16;
      float bvl = bias[col];
#pragma unroll
      for (int st = 0; st < 4; st++) {
#pragma unroll
        for (int r = 0; r < 4; r++) {
          int row = sblk + st * 16 + quad * 4 + r;
          dst[row * H_ + col] = f2bf(acc[st][i][r] + bvl);
        }
      }
    }
  } else {
#pragma unroll
    for (int i = 0; i < 4; i++) {
      int col = (wave * 4 + i) * 16 + l16;
      float bvl = bias[col];
#pragma unroll
      for (int st = 0; st < 4; st++) {
        int row0  = sblk + st * 16 + quad * 4;
        int b_idx = row0 >> 11;
        int k0    = row0 & (S_ - 1);
        bf16x4 pk;
#pragma unroll
        for (int r = 0; r < 4; r++) pk[r] = f2bf(acc[st][i][r] + bvl);
        *(bf16x4*)(VTo + (size_t)b_idx * H_ * S_ + (size_t)col * S_ + k0) = pk;
      }
    }
  }
}

// ---------------------------------------------------------------------------
// Kernel 2: P = exp(QK^T/256) in A-FRAGMENT-LINEARIZED layout; den += rowsums.
// Block = 256k x 128q (1024 blocks = b(8) x kt(8) x qt(16)); wave = 64k x 128q
// (4A x 8B = 32 MFMA/chunk). LDS staging 24 KiB; all ds_reads contiguous 1KiB.
// ---------------------------------------------------------------------------
__global__ __launch_bounds__(256) void scores(
    const short* __restrict__ Q, const short* __restrict__ K,
    short* __restrict__ Pf, float* __restrict__ den)
{
  const int tid  = threadIdx.x;
  const int wave = tid >> 6;
  const int lane = tid & 63;
  const int quad = lane >> 4;
  const int l16  = lane & 15;
  const int qt = blockIdx.x & 15;
  const int kt = (blockIdx.x >> 4) & 7;
  const int b  = blockIdx.x >> 7;

  const short* Qb = Q + b * S_ * H_;
  const short* Kb = K + b * S_ * H_;

  const int krow0 = kt * 256 + wave * 64;
  const int qcol0 = qt * 128;

  __shared__ short kbuf[16 * 512];   // K rows kt*256..+256 x 32-H chunk
  __shared__ short qbuf[8 * 512];    // Q rows qt*128..+128 x 32-H chunk

  f32x4 zero = {0.f, 0.f, 0.f, 0.f};
  f32x4 acc[4][8];
#pragma unroll
  for (int i = 0; i < 4; i++)
#pragma unroll
    for (int j = 0; j < 8; j++) acc[i][j] = zero;

  for (int ch = 0; ch < 8; ch++) {
#pragma unroll
    for (int i = 0; i < 4; i++) {
      int r = wave * 4 + i;
      gl_lds16(Kb + (kt * 256 + r * 16 + l16) * H_ + ch * 32 + quad * 8,
               kbuf + r * 512);
    }
#pragma unroll
    for (int i = 0; i < 2; i++) {
      int r = wave * 2 + i;
      gl_lds16(Qb + (qcol0 + r * 16 + l16) * H_ + ch * 32 + quad * 8,
               qbuf + r * 512);
    }
    __syncthreads();
    bf16x8 af[4];
#pragma unroll
    for (int i = 0; i < 4; i++)
      af[i] = *(const bf16x8*)(kbuf + (wave * 4 + i) * 512 + lane * 8);
#pragma unroll
    for (int qf = 0; qf < 8; qf++) {
      bf16x8 bq = *(const bf16x8*)(qbuf + qf * 512 + lane * 8);
#pragma unroll
      for (int i = 0; i < 4; i++)
        acc[i][qf] = mfma16(af[i], bq, acc[i][qf]);
    }
    __syncthreads();
  }

  const int j0 = (quad & 1) * 4;
  float rs[4][4] = {{0,0,0,0},{0,0,0,0},{0,0,0,0},{0,0,0,0}};
#pragma unroll
  for (int kf = 0; kf < 4; kf++) {
    int kw    = kt * 8 + wave * 2 + (kf >> 1);
    int quadA = 2 * (kf & 1) + (quad >> 1);
#pragma unroll
    for (int qf = 0; qf < 8; qf++) {
      bf16x4 pk;
#pragma unroll
      for (int r = 0; r < 4; r++) {
        float e = __expf(acc[kf][qf][r] * (1.0f / H_));
        rs[kf][r] += e;
        pk[r] = f2bf(e);
      }
      size_t tile = ((size_t)(b * 128 + qt * 8 + qf) << 6) + kw;
      *(bf16x4*)(Pf + (tile << 9) + (quadA * 16 + l16) * 8 + j0) = pk;
    }
  }

#pragma unroll
  for (int kf = 0; kf < 4; kf++) {
#pragma unroll
    for (int r = 0; r < 4; r++) {
      float v = rs[kf][r];
      v += __shfl_xor(v, 1, 64);
      v += __shfl_xor(v, 2, 64);
      v += __shfl_xor(v, 4, 64);
      v += __shfl_xor(v, 8, 64);
      if (l16 == 0)
        atomicAdd(&den[b * S_ + krow0 + kf * 16 + quad * 4 + r], v);
    }
  }
}

// ---------------------------------------------------------------------------
// Kernel 3: VT[b][h][k] /= den[b][k]  (fold softmax denom into V, rcp inline).
// ---------------------------------------------------------------------------
__global__ __launch_bounds__(256) void vscale(
    short* __restrict__ VT, const float* __restrict__ den)
{
  int i = blockIdx.x * 256 + threadIdx.x;
  int b  = i >> 17;
  int k0 = (i & 511) << 2;
  float4 df = *(const float4*)(den + b * S_ + k0);
  bf16x4 v = *(bf16x4*)(VT + (size_t)i * 4);
  bf16x4 o;
  o[0] = f2bf(bf2f(v[0]) / df.x);
  o[1] = f2bf(bf2f(v[1]) / df.y);
  o[2] = f2bf(bf2f(v[2]) / df.z);
  o[3] = f2bf(bf2f(v[3]) / df.w);
  *(bf16x4*)(VT + (size_t)i * 4) = o;
}

// ---------------------------------------------------------------------------
// Kernel 4: out = Pf . Vs — m97-style LDS-staged GEMM.
// grid 512: bx = qt*16 + b*2 + hs (same-(b,hs) blocks -> same XCD -> V in L2).
// ---------------------------------------------------------------------------
__global__ __launch_bounds__(256) void pv(
    const short* __restrict__ Pf, const short* __restrict__ VTs,
    float* __restrict__ out)
{
  const int tid  = threadIdx.x;
  const int wave = tid >> 6;
  const int lane = tid & 63;
  const int quad = lane >> 4;
  const int l16  = lane & 15;
  const int bx = blockIdx.x;
  const int qt = bx >> 4;
  const int b  = (bx >> 1) & 7;
  const int hs = bx & 1;

  __shared__ short vbuf[16 * 512];
  __shared__ short abuf[8 * 512];

  const int qt16 = qt * 4 + wave;
  const short* VTb = VTs + (size_t)b * H_ * S_ + (size_t)(hs * 128) * S_;
  const size_t tilebase = ((size_t)(b * 128 + qt16) * 64) << 9;

  f32x4 zero = {0.f, 0.f, 0.f, 0.f};
  f32x4 acc[8];
#pragma unroll
  for (int i = 0; i < 8; i++) acc[i] = zero;

  for (int kc = 0; kc < S_; kc += 64) {
#pragma unroll
    for (int i = 0; i < 4; i++) {
      int id = wave * 4 + i;
      int n  = id >> 1;
      int kw = id & 1;
      const short* g = VTb + (size_t)(n * 16 + l16) * S_ + kc + kw * 32 + quad * 8;
      gl_lds16(g, vbuf + id * 512);
    }
#pragma unroll
    for (int kwi = 0; kwi < 2; kwi++) {
      const short* g = Pf + tilebase + (size_t)((kc >> 5) + kwi) * 512 + lane * 8;
      gl_lds16(g, abuf + (wave * 2 + kwi) * 512);
    }
    __syncthreads();
#pragma unroll
    for (int kw = 0; kw < 2; kw++) {
      bf16x8 a = *(const bf16x8*)(abuf + (wave * 2 + kw) * 512 + lane * 8);
#pragma unroll
      for (int n = 0; n < 8; n++) {
        bf16x8 vb = *(const bf16x8*)(vbuf + (n * 2 + kw) * 512 + lane * 8);
        acc[n] = mfma16(a, vb, acc[n]);
      }
    }
    __syncthreads();
  }

  const int q0 = qt16 * 16;
#pragma unroll
  for (int n = 0; n < 8; n++) {
    int col = hs * 128 + n * 16 + l16;
#pragma unroll
    for (int r = 0; r < 4; r++) {
      int q = q0 + quad * 4 + r;
      out[((size_t)b * S_ + q) * H_ + col] = acc[n][r];
    }
  }
}

extern "C" void kernel_launch(void* const* d_in, const int* in_sizes, int n_in,
                              void* d_out, int out_size, void* d_ws, size_t ws_size,
                              hipStream_t stream) {
  const float* x  = (const float*)d_in[0];
  const float* Wq = (const float*)d_in[1];
  const float* bq = (const float*)d_in[2];
  const float* Wk = (const float*)d_in[3];
  const float* bk = (const float*)d_in[4];
  const float* Wv = (const float*)d_in[5];
  const float* bv = (const float*)d_in[6];

  short* xb  = (short*)d_ws;                       // 8 MiB
  short* wqb = xb  + (size_t)BS_ * H_;             // 128 KiB each
  short* wkb = wqb + H_ * H_;
  short* wvb = wkb + H_ * H_;
  short* Qs  = wvb + H_ * H_;                      // 8 MiB
  short* Ks  = Qs  + (size_t)BS_ * H_;             // 8 MiB
  short* VT  = Ks  + (size_t)BS_ * H_;             // 8 MiB
  short* P   = VT  + (size_t)BS_ * H_;             // 64 MiB (frag-linearized)
  float* den = (float*)(P + (size_t)B_ * S_ * S_); // 64 KiB
  float* outp = (float*)d_out;

  cvt_bf16<<<1024, 256, 0, stream>>>(x, Wq, Wk, Wv, xb, wqb, wkb, wvb, den);
  qkv_proj<<<dim3(BS_ / 64, 3), 256, 0, stream>>>(xb, wqb, bq, wkb, bk, wvb, bv, Qs, Ks, VT);
  scores<<<1024, 256, 0, stream>>>(Qs, Ks, P, den);
  vscale<<<4096, 256, 0, stream>>>(VT, den);
  pv<<<512, 256, 0, stream>>>(P, VT, outp);
}

// Round 10
// 194.639 us; speedup vs baseline: 1.0997x; 1.0997x over previous
//
#include <hip/hip_runtime.h>
#include <hip/hip_bf16.h>

#define B_ 8
#define S_ 2048
#define H_ 256
#define BS_ (B_*S_)

typedef __attribute__((ext_vector_type(8))) short bf16x8;
typedef __attribute__((ext_vector_type(4))) short bf16x4;
typedef __attribute__((ext_vector_type(4))) float f32x4;

static __device__ inline short f2bf(float f) {
  union { float f; unsigned int u; } a; a.f = f;
  unsigned int u = a.u;
  unsigned int r = (u + 0x7fffu + ((u >> 16) & 1u)) >> 16;
  return (short)r;
}

static __device__ inline float bf2f(short s) {
  union { float f; unsigned int u; } a;
  a.u = ((unsigned int)(unsigned short)s) << 16;
  return a.f;
}

static __device__ inline f32x4 mfma16(bf16x8 a, bf16x8 b, f32x4 c) {
  return __builtin_amdgcn_mfma_f32_16x16x32_bf16(a, b, c, 0, 0, 0);
}

// async global(16B/lane) -> LDS(wave-uniform base + lane*16)
static __device__ inline void gl_lds16(const short* g, short* l) {
  __builtin_amdgcn_global_load_lds(
      (const __attribute__((address_space(1))) void*)g,
      (__attribute__((address_space(3))) void*)l, 16, 0, 0);
}

// ---------------------------------------------------------------------------
// Kernel 0: fp32 -> bf16 conversion of x, Wq, Wk, Wv + zero den accumulator.
// ---------------------------------------------------------------------------
#define NX4 (BS_ * H_ / 4)
#define NW4 (H_ * H_ / 4)
#define NTOT4 (NX4 + 3 * NW4)
#define NALL4 (NTOT4 + BS_ / 4)

__global__ __launch_bounds__(256) void cvt_bf16(
    const float* __restrict__ x,
    const float* __restrict__ Wq, const float* __restrict__ Wk,
    const float* __restrict__ Wv,
    short* __restrict__ xb, short* __restrict__ wqb,
    short* __restrict__ wkb, short* __restrict__ wvb,
    float* __restrict__ den)
{
  int stride = gridDim.x * blockDim.x;
  for (int i = blockIdx.x * blockDim.x + threadIdx.x; i < NALL4; i += stride) {
    if (i >= NTOT4) {                        // zero den (0xAA-poisoned ws)
      float4 z = {0.f, 0.f, 0.f, 0.f};
      *(float4*)(den + (size_t)(i - NTOT4) * 4) = z;
      continue;
    }
    const float* src; short* dst; int off;
    if (i < NX4) { src = x; dst = xb; off = i; }
    else {
      int j = i - NX4;
      int w = j >> 14;
      off = j & (NW4 - 1);
      src = (w == 0) ? Wq : (w == 1) ? Wk : Wv;
      dst = (w == 0) ? wqb : (w == 1) ? wkb : wvb;
    }
    float4 v = *(const float4*)(src + off * 4);
    bf16x4 p;
    p[0] = f2bf(v.x); p[1] = f2bf(v.y); p[2] = f2bf(v.z); p[3] = f2bf(v.w);
    *(bf16x4*)(dst + off * 4) = p;
  }
}

// ---------------------------------------------------------------------------
// Kernel 1: Q/K row-major + V transposed [b][h][k]. grid (BS/64, 3), block 256.
// LDS-staged; wave = 64s x 64c (4A x 4B = 16 MFMA/chunk, 8 ds_reads/chunk).
// ---------------------------------------------------------------------------
__global__ __launch_bounds__(256) void qkv_proj(
    const short* __restrict__ x,
    const short* __restrict__ Wq, const float* __restrict__ bq,
    const short* __restrict__ Wk, const float* __restrict__ bk,
    const short* __restrict__ Wv, const float* __restrict__ bv,
    short* __restrict__ Qo, short* __restrict__ Ko, short* __restrict__ VTo)
{
  const int tid  = threadIdx.x;
  const int wave = tid >> 6;
  const int lane = tid & 63;
  const int quad = lane >> 4;
  const int l16  = lane & 15;
  const int y    = blockIdx.y;

  const short* W    = (y == 0) ? Wq : (y == 1) ? Wk : Wv;
  const float* bias = (y == 0) ? bq : (y == 1) ? bk : bv;
  const int sblk = blockIdx.x * 64;

  __shared__ short wbuf[16 * 512];   // all 256 W-rows x 32-K chunk
  __shared__ short xbuf[4 * 512];    // 64 X-rows x 32-K chunk

  f32x4 zero = {0.f, 0.f, 0.f, 0.f};
  f32x4 acc[4][4];                   // [s-tile][nf-rel]
#pragma unroll
  for (int i = 0; i < 4; i++)
#pragma unroll
    for (int j = 0; j < 4; j++) acc[i][j] = zero;

  for (int ch = 0; ch < 8; ch++) {
#pragma unroll
    for (int i = 0; i < 4; i++) {
      int r = wave * 4 + i;
      gl_lds16(W + (r * 16 + l16) * H_ + ch * 32 + quad * 8, wbuf + r * 512);
    }
    gl_lds16(x + (sblk + wave * 16 + l16) * H_ + ch * 32 + quad * 8,
             xbuf + wave * 512);
    __syncthreads();
    bf16x8 af[4];
#pragma unroll
    for (int st = 0; st < 4; st++)
      af[st] = *(const bf16x8*)(xbuf + st * 512 + lane * 8);
#pragma unroll
    for (int i = 0; i < 4; i++) {
      bf16x8 bb = *(const bf16x8*)(wbuf + (wave * 4 + i) * 512 + lane * 8);
#pragma unroll
      for (int st = 0; st < 4; st++)
        acc[st][i] = mfma16(af[st], bb, acc[st][i]);
    }
    __syncthreads();
  }

  if (y < 2) {
    short* dst = (y == 0) ? Qo : Ko;
#pragma unroll
    for (int i = 0; i < 4; i++) {
      int col = (wave * 4 + i) * 16 + l16;
      float bvl = bias[col];
#pragma unroll
      for (int st = 0; st < 4; st++) {
#pragma unroll
        for (int r = 0; r < 4; r++) {
          int row = sblk + st * 16 + quad * 4 + r;
          dst[row * H_ + col] = f2bf(acc[st][i][r] + bvl);
        }
      }
    }
  } else {
#pragma unroll
    for (int i = 0; i < 4; i++) {
      int col = (wave * 4 + i) * 16 + l16;
      float bvl = bias[col];
#pragma unroll
      for (int st = 0; st < 4; st++) {
        int row0  = sblk + st * 16 + quad * 4;
        int b_idx = row0 >> 11;
        int k0    = row0 & (S_ - 1);
        bf16x4 pk;
#pragma unroll
        for (int r = 0; r < 4; r++) pk[r] = f2bf(acc[st][i][r] + bvl);
        *(bf16x4*)(VTo + (size_t)b_idx * H_ * S_ + (size_t)col * S_ + k0) = pk;
      }
    }
  }
}

// ---------------------------------------------------------------------------
// Kernel 2: P = exp(QK^T/256) in A-FRAGMENT-LINEARIZED layout; den += rowsums.
// R8 tiling (measured 49 us): grid 2048 = b(8) x kt(16) x qt(16), block 256;
// wave = 32k x 128q, acc[2][8] (64 acc VGPRs -> ~80 total, ~25% occupancy).
// ---------------------------------------------------------------------------
__global__ __launch_bounds__(256) void scores(
    const short* __restrict__ Q, const short* __restrict__ K,
    short* __restrict__ Pf, float* __restrict__ den)
{
  const int tid  = threadIdx.x;
  const int wave = tid >> 6;
  const int lane = tid & 63;
  const int quad = lane >> 4;
  const int l16  = lane & 15;
  const int qt = blockIdx.x & 15;
  const int kt = (blockIdx.x >> 4) & 15;
  const int b  = blockIdx.x >> 8;

  const short* Qb = Q + b * S_ * H_;
  const short* Kb = K + b * S_ * H_;

  const int krow0 = kt * 128 + wave * 32;
  const int qcol0 = qt * 128;
  const int kw    = krow0 >> 5;

  __shared__ short kbuf[8 * 512];   // 8 KiB
  __shared__ short qbuf[8 * 512];   // 8 KiB

  f32x4 zero = {0.f, 0.f, 0.f, 0.f};
  f32x4 acc[2][8];
#pragma unroll
  for (int i = 0; i < 2; i++)
#pragma unroll
    for (int j = 0; j < 8; j++) acc[i][j] = zero;

  for (int ch = 0; ch < 8; ch++) {
#pragma unroll
    for (int i = 0; i < 2; i++) {
      int r = wave * 2 + i;
      gl_lds16(Kb + (kt * 128 + r * 16 + l16) * H_ + ch * 32 + quad * 8,
               kbuf + r * 512);
      gl_lds16(Qb + (qcol0 + r * 16 + l16) * H_ + ch * 32 + quad * 8,
               qbuf + r * 512);
    }
    __syncthreads();
    bf16x8 a0 = *(const bf16x8*)(kbuf + (wave * 2 + 0) * 512 + lane * 8);
    bf16x8 a1 = *(const bf16x8*)(kbuf + (wave * 2 + 1) * 512 + lane * 8);
#pragma unroll
    for (int qf = 0; qf < 8; qf++) {
      bf16x8 bq = *(const bf16x8*)(qbuf + qf * 512 + lane * 8);
      acc[0][qf] = mfma16(a0, bq, acc[0][qf]);
      acc[1][qf] = mfma16(a1, bq, acc[1][qf]);
    }
    __syncthreads();
  }

  const int quadA = quad >> 1;
  const int j0    = (quad & 1) * 4;
  float rs[2][4] = {{0.f,0.f,0.f,0.f},{0.f,0.f,0.f,0.f}};
#pragma unroll
  for (int kf = 0; kf < 2; kf++) {
#pragma unroll
    for (int qf = 0; qf < 8; qf++) {
      bf16x4 pk;
#pragma unroll
      for (int r = 0; r < 4; r++) {
        float e = __expf(acc[kf][qf][r] * (1.0f / H_));
        rs[kf][r] += e;
        pk[r] = f2bf(e);
      }
      size_t tile = ((size_t)(b * 128 + qt * 8 + qf) << 6) + kw;
      *(bf16x4*)(Pf + (tile << 9) + ((2 * kf + quadA) * 16 + l16) * 8 + j0) = pk;
    }
  }

#pragma unroll
  for (int kf = 0; kf < 2; kf++) {
#pragma unroll
    for (int r = 0; r < 4; r++) {
      float v = rs[kf][r];
      v += __shfl_xor(v, 1, 64);
      v += __shfl_xor(v, 2, 64);
      v += __shfl_xor(v, 4, 64);
      v += __shfl_xor(v, 8, 64);
      if (l16 == 0)
        atomicAdd(&den[b * S_ + krow0 + kf * 16 + quad * 4 + r], v);
    }
  }
}

// ---------------------------------------------------------------------------
// Kernel 3: VT[b][h][k] /= den[b][k]  (fold softmax denom into V, rcp inline).
// ---------------------------------------------------------------------------
__global__ __launch_bounds__(256) void vscale(
    short* __restrict__ VT, const float* __restrict__ den)
{
  int i = blockIdx.x * 256 + threadIdx.x;
  int b  = i >> 17;
  int k0 = (i & 511) << 2;
  float4 df = *(const float4*)(den + b * S_ + k0);
  bf16x4 v = *(bf16x4*)(VT + (size_t)i * 4);
  bf16x4 o;
  o[0] = f2bf(bf2f(v[0]) / df.x);
  o[1] = f2bf(bf2f(v[1]) / df.y);
  o[2] = f2bf(bf2f(v[2]) / df.z);
  o[3] = f2bf(bf2f(v[3]) / df.w);
  *(bf16x4*)(VT + (size_t)i * 4) = o;
}

// ---------------------------------------------------------------------------
// Kernel 4: out = Pf . Vs — m97-style LDS-staged GEMM.
// grid 512: bx = qt*16 + b*2 + hs (same-(b,hs) blocks -> same XCD -> V in L2).
// ---------------------------------------------------------------------------
__global__ __launch_bounds__(256) void pv(
    const short* __restrict__ Pf, const short* __restrict__ VTs,
    float* __restrict__ out)
{
  const int tid  = threadIdx.x;
  const int wave = tid >> 6;
  const int lane = tid & 63;
  const int quad = lane >> 4;
  const int l16  = lane & 15;
  const int bx = blockIdx.x;
  const int qt = bx >> 4;
  const int b  = (bx >> 1) & 7;
  const int hs = bx & 1;

  __shared__ short vbuf[16 * 512];
  __shared__ short abuf[8 * 512];

  const int qt16 = qt * 4 + wave;
  const short* VTb = VTs + (size_t)b * H_ * S_ + (size_t)(hs * 128) * S_;
  const size_t tilebase = ((size_t)(b * 128 + qt16) * 64) << 9;

  f32x4 zero = {0.f, 0.f, 0.f, 0.f};
  f32x4 acc[8];
#pragma unroll
  for (int i = 0; i < 8; i++) acc[i] = zero;

  for (int kc = 0; kc < S_; kc += 64) {
#pragma unroll
    for (int i = 0; i < 4; i++) {
      int id = wave * 4 + i;
      int n  = id >> 1;
      int kw = id & 1;
      const short* g = VTb + (size_t)(n * 16 + l16) * S_ + kc + kw * 32 + quad * 8;
      gl_lds16(g, vbuf + id * 512);
    }
#pragma unroll
    for (int kwi = 0; kwi < 2; kwi++) {
      const short* g = Pf + tilebase + (size_t)((kc >> 5) + kwi) * 512 + lane * 8;
      gl_lds16(g, abuf + (wave * 2 + kwi) * 512);
    }
    __syncthreads();
#pragma unroll
    for (int kw = 0; kw < 2; kw++) {
      bf16x8 a = *(const bf16x8*)(abuf + (wave * 2 + kw) * 512 + lane * 8);
#pragma unroll
      for (int n = 0; n < 8; n++) {
        bf16x8 vb = *(const bf16x8*)(vbuf + (n * 2 + kw) * 512 + lane * 8);
        acc[n] = mfma16(a, vb, acc[n]);
      }
    }
    __syncthreads();
  }

  const int q0 = qt16 * 16;
#pragma unroll
  for (int n = 0; n < 8; n++) {
    int col = hs * 128 + n * 16 + l16;
#pragma unroll
    for (int r = 0; r < 4; r++) {
      int q = q0 + quad * 4 + r;
      out[((size_t)b * S_ + q) * H_ + col] = acc[n][r];
    }
  }
}

extern "C" void kernel_launch(void* const* d_in, const int* in_sizes, int n_in,
                              void* d_out, int out_size, void* d_ws, size_t ws_size,
                              hipStream_t stream) {
  const float* x  = (const float*)d_in[0];
  const float* Wq = (const float*)d_in[1];
  const float* bq = (const float*)d_in[2];
  const float* Wk = (const float*)d_in[3];
  const float* bk = (const float*)d_in[4];
  const float* Wv = (const float*)d_in[5];
  const float* bv = (const float*)d_in[6];

  short* xb  = (short*)d_ws;                       // 8 MiB
  short* wqb = xb  + (size_t)BS_ * H_;             // 128 KiB each
  short* wkb = wqb + H_ * H_;
  short* wvb = wkb + H_ * H_;
  short* Qs  = wvb + H_ * H_;                      // 8 MiB
  short* Ks  = Qs  + (size_t)BS_ * H_;             // 8 MiB
  short* VT  = Ks  + (size_t)BS_ * H_;             // 8 MiB
  short* P   = VT  + (size_t)BS_ * H_;             // 64 MiB (frag-linearized)
  float* den = (float*)(P + (size_t)B_ * S_ * S_); // 64 KiB
  float* outp = (float*)d_out;

  cvt_bf16<<<1024, 256, 0, stream>>>(x, Wq, Wk, Wv, xb, wqb, wkb, wvb, den);
  qkv_proj<<<dim3(BS_ / 64, 3), 256, 0, stream>>>(xb, wqb, bq, wkb, bk, wvb, bv, Qs, Ks, VT);
  scores<<<2048, 256, 0, stream>>>(Qs, Ks, P, den);
  vscale<<<4096, 256, 0, stream>>>(VT, den);
  pv<<<512, 256, 0, stream>>>(P, VT, outp);
}

// Round 11
// 185.471 us; speedup vs baseline: 1.1540x; 1.0494x over previous
//
#include <hip/hip_runtime.h>
#include <hip/hip_bf16.h>

#define B_ 8
#define S_ 2048
#define H_ 256
#define BS_ (B_*S_)

typedef __attribute__((ext_vector_type(8))) short bf16x8;
typedef __attribute__((ext_vector_type(4))) short bf16x4;
typedef __attribute__((ext_vector_type(4))) float f32x4;

static __device__ inline short f2bf(float f) {
  union { float f; unsigned int u; } a; a.f = f;
  unsigned int u = a.u;
  unsigned int r = (u + 0x7fffu + ((u >> 16) & 1u)) >> 16;
  return (short)r;
}

static __device__ inline float bf2f(short s) {
  union { float f; unsigned int u; } a;
  a.u = ((unsigned int)(unsigned short)s) << 16;
  return a.f;
}

static __device__ inline f32x4 mfma16(bf16x8 a, bf16x8 b, f32x4 c) {
  return __builtin_amdgcn_mfma_f32_16x16x32_bf16(a, b, c, 0, 0, 0);
}

// async global(16B/lane) -> LDS(wave-uniform base + lane*16)
static __device__ inline void gl_lds16(const short* g, short* l) {
  __builtin_amdgcn_global_load_lds(
      (const __attribute__((address_space(1))) void*)g,
      (__attribute__((address_space(3))) void*)l, 16, 0, 0);
}

// ---------------------------------------------------------------------------
// Kernel 0: fp32 -> bf16 conversion of x, Wq, Wk, Wv + zero den accumulator.
// ---------------------------------------------------------------------------
#define NX4 (BS_ * H_ / 4)
#define NW4 (H_ * H_ / 4)
#define NTOT4 (NX4 + 3 * NW4)
#define NALL4 (NTOT4 + BS_ / 4)

__global__ __launch_bounds__(256) void cvt_bf16(
    const float* __restrict__ x,
    const float* __restrict__ Wq, const float* __restrict__ Wk,
    const float* __restrict__ Wv,
    short* __restrict__ xb, short* __restrict__ wqb,
    short* __restrict__ wkb, short* __restrict__ wvb,
    float* __restrict__ den)
{
  int stride = gridDim.x * blockDim.x;
  for (int i = blockIdx.x * blockDim.x + threadIdx.x; i < NALL4; i += stride) {
    if (i >= NTOT4) {                        // zero den (0xAA-poisoned ws)
      float4 z = {0.f, 0.f, 0.f, 0.f};
      *(float4*)(den + (size_t)(i - NTOT4) * 4) = z;
      continue;
    }
    const float* src; short* dst; int off;
    if (i < NX4) { src = x; dst = xb; off = i; }
    else {
      int j = i - NX4;
      int w = j >> 14;
      off = j & (NW4 - 1);
      src = (w == 0) ? Wq : (w == 1) ? Wk : Wv;
      dst = (w == 0) ? wqb : (w == 1) ? wkb : wvb;
    }
    float4 v = *(const float4*)(src + off * 4);
    bf16x4 p;
    p[0] = f2bf(v.x); p[1] = f2bf(v.y); p[2] = f2bf(v.z); p[3] = f2bf(v.w);
    *(bf16x4*)(dst + off * 4) = p;
  }
}

// ---------------------------------------------------------------------------
// Kernel 1: Q/K row-major + V transposed [b][h][k]. grid (BS/64, 3), block 256.
// LDS-staged; wave = 64s x 64c.
// ---------------------------------------------------------------------------
__global__ __launch_bounds__(256) void qkv_proj(
    const short* __restrict__ x,
    const short* __restrict__ Wq, const float* __restrict__ bq,
    const short* __restrict__ Wk, const float* __restrict__ bk,
    const short* __restrict__ Wv, const float* __restrict__ bv,
    short* __restrict__ Qo, short* __restrict__ Ko, short* __restrict__ VTo)
{
  const int tid  = threadIdx.x;
  const int wave = tid >> 6;
  const int lane = tid & 63;
  const int quad = lane >> 4;
  const int l16  = lane & 15;
  const int y    = blockIdx.y;

  const short* W    = (y == 0) ? Wq : (y == 1) ? Wk : Wv;
  const float* bias = (y == 0) ? bq : (y == 1) ? bk : bv;
  const int sblk = blockIdx.x * 64;

  __shared__ short wbuf[16 * 512];
  __shared__ short xbuf[4 * 512];

  f32x4 zero = {0.f, 0.f, 0.f, 0.f};
  f32x4 acc[4][4];
#pragma unroll
  for (int i = 0; i < 4; i++)
#pragma unroll
    for (int j = 0; j < 4; j++) acc[i][j] = zero;

  for (int ch = 0; ch < 8; ch++) {
#pragma unroll
    for (int i = 0; i < 4; i++) {
      int r = wave * 4 + i;
      gl_lds16(W + (r * 16 + l16) * H_ + ch * 32 + quad * 8, wbuf + r * 512);
    }
    gl_lds16(x + (sblk + wave * 16 + l16) * H_ + ch * 32 + quad * 8,
             xbuf + wave * 512);
    __syncthreads();
    bf16x8 af[4];
#pragma unroll
    for (int st = 0; st < 4; st++)
      af[st] = *(const bf16x8*)(xbuf + st * 512 + lane * 8);
#pragma unroll
    for (int i = 0; i < 4; i++) {
      bf16x8 bb = *(const bf16x8*)(wbuf + (wave * 4 + i) * 512 + lane * 8);
#pragma unroll
      for (int st = 0; st < 4; st++)
        acc[st][i] = mfma16(af[st], bb, acc[st][i]);
    }
    __syncthreads();
  }

  if (y < 2) {
    short* dst = (y == 0) ? Qo : Ko;
#pragma unroll
    for (int i = 0; i < 4; i++) {
      int col = (wave * 4 + i) * 16 + l16;
      float bvl = bias[col];
#pragma unroll
      for (int st = 0; st < 4; st++) {
#pragma unroll
        for (int r = 0; r < 4; r++) {
          int row = sblk + st * 16 + quad * 4 + r;
          dst[row * H_ + col] = f2bf(acc[st][i][r] + bvl);
        }
      }
    }
  } else {
#pragma unroll
    for (int i = 0; i < 4; i++) {
      int col = (wave * 4 + i) * 16 + l16;
      float bvl = bias[col];
#pragma unroll
      for (int st = 0; st < 4; st++) {
        int row0  = sblk + st * 16 + quad * 4;
        int b_idx = row0 >> 11;
        int k0    = row0 & (S_ - 1);
        bf16x4 pk;
#pragma unroll
        for (int r = 0; r < 4; r++) pk[r] = f2bf(acc[st][i][r] + bvl);
        *(bf16x4*)(VTo + (size_t)b_idx * H_ * S_ + (size_t)col * S_ + k0) = pk;
      }
    }
  }
}

// ---------------------------------------------------------------------------
// Kernel 2: P = exp(QK^T/256) in A-FRAGMENT-LINEARIZED layout; den += rowsums.
// R8 tiling, CH=64 staging (4 chunks, 8 barriers): grid 2048, block 256;
// wave = 32k x 128q, acc[2][8]. LDS 32 KiB: region (r, hw) = 16 rows x 32 H.
// ---------------------------------------------------------------------------
__global__ __launch_bounds__(256) void scores(
    const short* __restrict__ Q, const short* __restrict__ K,
    short* __restrict__ Pf, float* __restrict__ den)
{
  const int tid  = threadIdx.x;
  const int wave = tid >> 6;
  const int lane = tid & 63;
  const int quad = lane >> 4;
  const int l16  = lane & 15;
  const int qt = blockIdx.x & 15;
  const int kt = (blockIdx.x >> 4) & 15;
  const int b  = blockIdx.x >> 8;

  const short* Qb = Q + b * S_ * H_;
  const short* Kb = K + b * S_ * H_;

  const int krow0 = kt * 128 + wave * 32;
  const int qcol0 = qt * 128;
  const int kw    = krow0 >> 5;

  __shared__ short kbuf[16 * 512];   // 16 KiB: 128 k-rows x 64-H chunk
  __shared__ short qbuf[16 * 512];   // 16 KiB: 128 q-rows x 64-H chunk

  f32x4 zero = {0.f, 0.f, 0.f, 0.f};
  f32x4 acc[2][8];
#pragma unroll
  for (int i = 0; i < 2; i++)
#pragma unroll
    for (int j = 0; j < 8; j++) acc[i][j] = zero;

  for (int ch = 0; ch < 4; ch++) {
#pragma unroll
    for (int i = 0; i < 2; i++) {
      int r = wave * 2 + i;
#pragma unroll
      for (int hw = 0; hw < 2; hw++) {
        gl_lds16(Kb + (kt * 128 + r * 16 + l16) * H_ + ch * 64 + hw * 32 + quad * 8,
                 kbuf + (r * 2 + hw) * 512);
        gl_lds16(Qb + (qcol0 + r * 16 + l16) * H_ + ch * 64 + hw * 32 + quad * 8,
                 qbuf + (r * 2 + hw) * 512);
      }
    }
    __syncthreads();
#pragma unroll
    for (int hw = 0; hw < 2; hw++) {
      bf16x8 a0 = *(const bf16x8*)(kbuf + ((wave * 2 + 0) * 2 + hw) * 512 + lane * 8);
      bf16x8 a1 = *(const bf16x8*)(kbuf + ((wave * 2 + 1) * 2 + hw) * 512 + lane * 8);
#pragma unroll
      for (int qf = 0; qf < 8; qf++) {
        bf16x8 bq = *(const bf16x8*)(qbuf + (qf * 2 + hw) * 512 + lane * 8);
        acc[0][qf] = mfma16(a0, bq, acc[0][qf]);
        acc[1][qf] = mfma16(a1, bq, acc[1][qf]);
      }
    }
    __syncthreads();
  }

  const int quadA = quad >> 1;
  const int j0    = (quad & 1) * 4;
  float rs[2][4] = {{0.f,0.f,0.f,0.f},{0.f,0.f,0.f,0.f}};
#pragma unroll
  for (int kf = 0; kf < 2; kf++) {
#pragma unroll
    for (int qf = 0; qf < 8; qf++) {
      bf16x4 pk;
#pragma unroll
      for (int r = 0; r < 4; r++) {
        float e = __expf(acc[kf][qf][r] * (1.0f / H_));
        rs[kf][r] += e;
        pk[r] = f2bf(e);
      }
      size_t tile = ((size_t)(b * 128 + qt * 8 + qf) << 6) + kw;
      *(bf16x4*)(Pf + (tile << 9) + ((2 * kf + quadA) * 16 + l16) * 8 + j0) = pk;
    }
  }

#pragma unroll
  for (int kf = 0; kf < 2; kf++) {
#pragma unroll
    for (int r = 0; r < 4; r++) {
      float v = rs[kf][r];
      v += __shfl_xor(v, 1, 64);
      v += __shfl_xor(v, 2, 64);
      v += __shfl_xor(v, 4, 64);
      v += __shfl_xor(v, 8, 64);
      if (l16 == 0)
        atomicAdd(&den[b * S_ + krow0 + kf * 16 + quad * 4 + r], v);
    }
  }
}

// ---------------------------------------------------------------------------
// Kernel 3: VT[b][h][k] /= den[b][k]  (fold softmax denom into V, rcp inline).
// ---------------------------------------------------------------------------
__global__ __launch_bounds__(256) void vscale(
    short* __restrict__ VT, const float* __restrict__ den)
{
  int i = blockIdx.x * 256 + threadIdx.x;
  int b  = i >> 17;
  int k0 = (i & 511) << 2;
  float4 df = *(const float4*)(den + b * S_ + k0);
  bf16x4 v = *(bf16x4*)(VT + (size_t)i * 4);
  bf16x4 o;
  o[0] = f2bf(bf2f(v[0]) / df.x);
  o[1] = f2bf(bf2f(v[1]) / df.y);
  o[2] = f2bf(bf2f(v[2]) / df.z);
  o[3] = f2bf(bf2f(v[3]) / df.w);
  *(bf16x4*)(VT + (size_t)i * 4) = o;
}

// ---------------------------------------------------------------------------
// Kernel 4: out = Pf . Vs — LDS-staged GEMM, BK=128 (16 chunks, 32 barriers).
// grid 512: bx = qt*16 + b*2 + hs (same-(b,hs) blocks -> same XCD -> V in L2).
// LDS 48 KiB: vbuf 32 regions (n,kw), abuf 16 regions (wave,kw).
// ---------------------------------------------------------------------------
__global__ __launch_bounds__(256) void pv(
    const short* __restrict__ Pf, const short* __restrict__ VTs,
    float* __restrict__ out)
{
  const int tid  = threadIdx.x;
  const int wave = tid >> 6;
  const int lane = tid & 63;
  const int quad = lane >> 4;
  const int l16  = lane & 15;
  const int bx = blockIdx.x;
  const int qt = bx >> 4;
  const int b  = (bx >> 1) & 7;
  const int hs = bx & 1;

  __shared__ short vbuf[32 * 512];   // 32 KiB
  __shared__ short abuf[16 * 512];   // 16 KiB

  const int qt16 = qt * 4 + wave;
  const short* VTb = VTs + (size_t)b * H_ * S_ + (size_t)(hs * 128) * S_;
  const size_t tilebase = ((size_t)(b * 128 + qt16) * 64) << 9;

  f32x4 zero = {0.f, 0.f, 0.f, 0.f};
  f32x4 acc[8];
#pragma unroll
  for (int i = 0; i < 8; i++) acc[i] = zero;

  for (int kc = 0; kc < S_; kc += 128) {
    // stage V: 32 regions, 8 per wave
#pragma unroll
    for (int i = 0; i < 8; i++) {
      int id = wave * 8 + i;
      int n  = id >> 2;
      int kw = id & 3;
      const short* g = VTb + (size_t)(n * 16 + l16) * S_ + kc + kw * 32 + quad * 8;
      gl_lds16(g, vbuf + id * 512);
    }
    // stage A: 4 regions per wave
#pragma unroll
    for (int kwi = 0; kwi < 4; kwi++) {
      const short* g = Pf + tilebase + (size_t)((kc >> 5) + kwi) * 512 + lane * 8;
      gl_lds16(g, abuf + (wave * 4 + kwi) * 512);
    }
    __syncthreads();
#pragma unroll
    for (int kw = 0; kw < 4; kw++) {
      bf16x8 a = *(const bf16x8*)(abuf + (wave * 4 + kw) * 512 + lane * 8);
#pragma unroll
      for (int n = 0; n < 8; n++) {
        bf16x8 vb = *(const bf16x8*)(vbuf + (n * 4 + kw) * 512 + lane * 8);
        acc[n] = mfma16(a, vb, acc[n]);
      }
    }
    __syncthreads();
  }

  const int q0 = qt16 * 16;
#pragma unroll
  for (int n = 0; n < 8; n++) {
    int col = hs * 128 + n * 16 + l16;
#pragma unroll
    for (int r = 0; r < 4; r++) {
      int q = q0 + quad * 4 + r;
      out[((size_t)b * S_ + q) * H_ + col] = acc[n][r];
    }
  }
}

extern "C" void kernel_launch(void* const* d_in, const int* in_sizes, int n_in,
                              void* d_out, int out_size, void* d_ws, size_t ws_size,
                              hipStream_t stream) {
  const float* x  = (const float*)d_in[0];
  const float* Wq = (const float*)d_in[1];
  const float* bq = (const float*)d_in[2];
  const float* Wk = (const float*)d_in[3];
  const float* bk = (const float*)d_in[4];
  const float* Wv = (const float*)d_in[5];
  const float* bv = (const float*)d_in[6];

  short* xb  = (short*)d_ws;                       // 8 MiB
  short* wqb = xb  + (size_t)BS_ * H_;             // 128 KiB each
  short* wkb = wqb + H_ * H_;
  short* wvb = wkb + H_ * H_;
  short* Qs  = wvb + H_ * H_;                      // 8 MiB
  short* Ks  = Qs  + (size_t)BS_ * H_;             // 8 MiB
  short* VT  = Ks  + (size_t)BS_ * H_;             // 8 MiB
  short* P   = VT  + (size_t)BS_ * H_;             // 64 MiB (frag-linearized)
  float* den = (float*)(P + (size_t)B_ * S_ * S_); // 64 KiB
  float* outp = (float*)d_out;

  cvt_bf16<<<1024, 256, 0, stream>>>(x, Wq, Wk, Wv, xb, wqb, wkb, wvb, den);
  qkv_proj<<<dim3(BS_ / 64, 3), 256, 0, stream>>>(xb, wqb, bq, wkb, bk, wvb, bv, Qs, Ks, VT);
  scores<<<2048, 256, 0, stream>>>(Qs, Ks, P, den);
  vscale<<<4096, 256, 0, stream>>>(VT, den);
  pv<<<512, 256, 0, stream>>>(P, VT, outp);
}